// Round 2
// baseline (160.295 us; speedup 1.0000x reference)
//
#include <hip/hip_runtime.h>
#include <hip/hip_bf16.h>

// n=8192 rows, d=256 feat, 10 classes.
// loss = mean_i log1p(exp(0.5/0.7) * A_i * B_i)
//   A_i = sum_{j: y_j!=y_i} exp(sim_ij/0.7), B_i = sum_{j!=i: y_j==y_i} exp(-sim_ij/0.7)
//   sim = rownorm(P) @ rownorm(P)^T
//
// R9: R8 (symmetry: block (I,C), rows panel I of 128 x col group C of 256,
// exists iff I < 2C+2, col-accumulate iff I < 2C) halved the compute but its
// col-side device-scope atomics exploded HBM traffic (WRITE 5.8->68.5MB:
// ~500K contended cross-XCD atomics, each a memory-side 64B RMW). Fix: each
// colacc block stores its 512 col-partials to a PRIVATE colPart[bid] slot
// (plain coalesced stores, no contention); new k_reduce (32 blocks) sums the
// 2C partials per column group and adds into Aacc/Bacc non-atomically.
// Row-side atomics kept (proven cheap in R7: 262K ops, 5.8MB).

#define NF 256
#define TINV (1.0f / 0.7f)
#define SC2 2.0609929398439434f  // (1/0.7)*log2(e)

typedef __attribute__((ext_vector_type(8))) short short8;
typedef __attribute__((ext_vector_type(4))) float float4v;

typedef const __attribute__((address_space(1))) unsigned int glb_u32;
typedef __attribute__((address_space(3))) unsigned int lds_u32;

// One wave per row: normalize to bf16. Also zeroes the accumulators.
__global__ __launch_bounds__(256)
void k_prep(const float* __restrict__ P, unsigned short* __restrict__ Pn,
            float* __restrict__ AB) {  // AB = Aacc||Bacc, 2n floats
    int wave = threadIdx.x >> 6, lane = threadIdx.x & 63;
    int row = blockIdx.x * 4 + wave;
    if (threadIdx.x < 8) AB[blockIdx.x * 8 + threadIdx.x] = 0.f;
    float4 v = *(const float4*)(P + (size_t)row * NF + lane * 4);
    float sq = v.x * v.x + v.y * v.y + v.z * v.z + v.w * v.w;
#pragma unroll
    for (int off = 32; off; off >>= 1) sq += __shfl_xor(sq, off, 64);
    float r = rsqrtf(sq);
    __hip_bfloat16 h0 = __float2bfloat16(v.x * r), h1 = __float2bfloat16(v.y * r),
                   h2 = __float2bfloat16(v.z * r), h3 = __float2bfloat16(v.w * r);
    ushort4 o = { *(unsigned short*)&h0, *(unsigned short*)&h1,
                  *(unsigned short*)&h2, *(unsigned short*)&h3 };
    *(ushort4*)(Pn + (size_t)row * NF + lane * 4) = o;
}

__global__ __launch_bounds__(256, 3)
void k_main(const unsigned short* __restrict__ Pn, const int* __restrict__ y,
            float* __restrict__ Aacc, float* __restrict__ Bacc,
            float* __restrict__ colPart) {
    // B chunk: 64 cols x K=256, kc-major: ushort addr = kc*512 + col*8
    __shared__ __align__(16) unsigned short Bs[64 * NF];
    __shared__ int yc[256];
    __shared__ float colA[256], colB[256];

    const int tid = threadIdx.x;
    // Decode (I, C): cumulative blocks before group C is C*(C+1).
    int bid = blockIdx.x;
    int C = (int)((sqrtf(4.0f * (float)bid + 1.0f) - 1.0f) * 0.5f);
    while (C * (C + 1) > bid) --C;
    while ((C + 1) * (C + 2) <= bid) ++C;
    const int I = bid - C * (C + 1);          // row panel, I in [0, 2C+2)
    const int rb = I * 128, cb0 = C * 256;
    const bool colacc = (C > (I >> 1));       // uniform: col panels strictly above row panel

    const int lane = tid & 63, wave = tid >> 6;
    const int quad = lane >> 4, l15 = lane & 15;

    // DMA one 64-col chunk: 32 instrs (8 per wave), lane L -> col L.
    // kc-instr: lane L reads Pn[(cb0+c*64+L)*NF + kc*8], lands at kc*1024+L*16 B.
#define DMA_CHUNK(c)                                                          \
    {                                                                         \
        _Pragma("unroll")                                                     \
        for (int i = 0; i < 8; ++i) {                                         \
            const int kc = wave * 8 + i;                                      \
            const unsigned short* src =                                       \
                Pn + (size_t)(cb0 + (c) * 64 + lane) * NF + kc * 8;           \
            __builtin_amdgcn_global_load_lds((glb_u32*)src,                   \
                (lds_u32*)&Bs[kc * 512], 16, 0, 0);                           \
        }                                                                     \
    }

    DMA_CHUNK(0)   // issue first so DMA latency overlaps A-frag loads

    yc[tid] = y[cb0 + tid];
    colA[tid] = 0.f;
    colB[tid] = 0.f;

    // A-frags: this wave's 32 rows x full K. m=l15, k=quad*8+j (16x16x32).
    const unsigned short* pa = Pn + (size_t)(rb + wave * 32 + l15) * NF + quad * 8;
    short8 afr[2][8];
#pragma unroll
    for (int tr = 0; tr < 2; ++tr)
#pragma unroll
        for (int ks = 0; ks < 8; ++ks)
            afr[tr][ks] = *(const short8*)(pa + (size_t)tr * 16 * NF + ks * 32);

    // Row classes byte-packed (rows tr*16 + quad*4 + r).
    unsigned yis[2];
#pragma unroll
    for (int tr = 0; tr < 2; ++tr) {
        int4 v = *(const int4*)(y + rb + wave * 32 + tr * 16 + quad * 4);
        yis[tr] = (unsigned)(v.x & 255) | ((unsigned)(v.y & 255) << 8) |
                  ((unsigned)(v.z & 255) << 16) | ((unsigned)(v.w & 255) << 24);
    }

    float rA[2][4], rB[2][4];
#pragma unroll
    for (int tr = 0; tr < 2; ++tr)
#pragma unroll
        for (int r = 0; r < 4; ++r) { rA[tr][r] = 0.f; rB[tr][r] = 0.f; }

#pragma unroll 1
    for (int c = 0; c < 4; ++c) {
        __syncthreads();   // own-vmcnt drained by compiler before barrier -> Bs ready

        float4v acc[2][4];
#pragma unroll
        for (int a = 0; a < 2; ++a)
#pragma unroll
            for (int b = 0; b < 4; ++b) acc[a][b] = (float4v){0.f, 0.f, 0.f, 0.f};

#pragma unroll
        for (int ks = 0; ks < 8; ++ks) {
            short8 fb[4];
#pragma unroll
            for (int tc = 0; tc < 4; ++tc)
                fb[tc] = *(const short8*)&Bs[(ks * 4 + quad) * 512 + (tc * 16 + l15) * 8];
#pragma unroll
            for (int tr = 0; tr < 2; ++tr)
#pragma unroll
                for (int tc = 0; tc < 4; ++tc)
                    acc[tr][tc] = __builtin_amdgcn_mfma_f32_16x16x32_bf16(
                        afr[tr][ks], fb[tc], acc[tr][tc], 0, 0, 0);
        }
        __syncthreads();   // all waves done reading Bs
        if (c < 3) DMA_CHUNK(c + 1)

        // Fused epilogue. C/D: col=l15, row=quad*4+reg.
#pragma unroll
        for (int tc = 0; tc < 4; ++tc) {
            const int jl = c * 64 + tc * 16 + l15;
            const int yj = yc[jl];
            const int gj = cb0 + jl;
            float ca = 0.f, cbv = 0.f;   // column partials (sum over this wave's 32 rows)
#pragma unroll
            for (int tr = 0; tr < 2; ++tr) {
                const int gi0 = rb + wave * 32 + tr * 16 + quad * 4;
#pragma unroll
                for (int r = 0; r < 4; ++r) {
                    const float s = acc[tr][tc][r];
                    const int cls = (yis[tr] >> (8 * r)) & 255;
                    const bool same = (cls == yj);
                    const float e = exp2f(s * (same ? -SC2 : SC2));
                    rA[tr][r] += same ? 0.f : e;
                    rB[tr][r] += (same && (gi0 + r != gj)) ? e : 0.f;
                    ca  += same ? 0.f : e;   // col-side: gi != gj guaranteed when colacc
                    cbv += same ? e : 0.f;
                }
            }
            if (colacc) {   // uniform branch
                ca  += __shfl_xor(ca, 16, 64);  ca  += __shfl_xor(ca, 32, 64);
                cbv += __shfl_xor(cbv, 16, 64); cbv += __shfl_xor(cbv, 32, 64);
                if (quad == 0) {
                    atomicAdd(&colA[jl], ca);
                    atomicAdd(&colB[jl], cbv);
                }
            }
        }
    }

    // Row side: butterfly over 16 col-lanes; quad leaders issue atomics.
#pragma unroll
    for (int tr = 0; tr < 2; ++tr)
#pragma unroll
        for (int r = 0; r < 4; ++r) {
#pragma unroll
            for (int off = 1; off < 16; off <<= 1) {
                rA[tr][r] += __shfl_xor(rA[tr][r], off, 64);
                rB[tr][r] += __shfl_xor(rB[tr][r], off, 64);
            }
        }
    if (l15 == 0) {
#pragma unroll
        for (int tr = 0; tr < 2; ++tr)
#pragma unroll
            for (int r = 0; r < 4; ++r) {
                const int gi = rb + wave * 32 + tr * 16 + quad * 4 + r;
                atomicAdd(&Aacc[gi], rA[tr][r]);
                atomicAdd(&Bacc[gi], rB[tr][r]);
            }
    }

    // Column side: private per-block partial dump (plain coalesced stores).
    if (colacc) {
        __syncthreads();   // all waves' chunk-3 LDS atomics done (uniform branch)
        float* cp = colPart + (size_t)bid * 512;
        cp[tid] = colA[tid];
        cp[256 + tid] = colB[tid];
    }
}

// Sum per-block column partials into Aacc/Bacc. One thread per column.
// Group C's colacc blocks are bid = C*(C+1)+I for I in [0, 2C). Runs after
// k_main, so plain read-modify-write is race-free.
__global__ __launch_bounds__(256)
void k_reduce(const float* __restrict__ colPart, float* __restrict__ Aacc,
              float* __restrict__ Bacc) {
    const int j = blockIdx.x * 256 + threadIdx.x;  // column 0..8191
    const int C = j >> 8, o = j & 255;
    const float* p = colPart + (size_t)(C * (C + 1)) * 512 + o;
    float sA = 0.f, sB = 0.f;
    for (int I = 0; I < 2 * C; ++I) {
        sA += p[0];
        sB += p[256];
        p += 512;
    }
    Aacc[j] += sA;
    Bacc[j] += sB;
}

// Single block: ballot-based class histogram, mean loss, direct write of out[0].
__global__ __launch_bounds__(1024)
void k_final(const float* __restrict__ Aacc, const float* __restrict__ Bacc,
             const int* __restrict__ y, float* __restrict__ out, int n) {
    __shared__ int hist[16];
    __shared__ float red[16];
    const int tid = threadIdx.x;
    if (tid < 16) hist[tid] = 0;
    __syncthreads();
    int loc[10];
#pragma unroll
    for (int cc = 0; cc < 10; ++cc) loc[cc] = 0;
    for (int i = tid; i < n; i += 1024) {
        const int yv = y[i];
#pragma unroll
        for (int cc = 0; cc < 10; ++cc) {
            unsigned long long m = __ballot(yv == cc);
            if ((tid & 63) == 0) loc[cc] += __popcll(m);
        }
    }
    if ((tid & 63) == 0)
#pragma unroll
        for (int cc = 0; cc < 10; ++cc) atomicAdd(&hist[cc], loc[cc]);
    __syncthreads();
    const float M = __expf(0.5f * TINV);
    float s = 0.f;
    for (int i = tid; i < n; i += 1024) {
        const int cc = hist[y[i] & 15];
        const float a = (n - cc) > 0 ? Aacc[i] : 1.0f;
        const float b = (cc - 1) > 0 ? Bacc[i] : 1.0f;
        s += log1pf(M * a * b);
    }
#pragma unroll
    for (int off = 32; off; off >>= 1) s += __shfl_xor(s, off, 64);
    if ((tid & 63) == 0) red[tid >> 6] = s;
    __syncthreads();
    if (tid == 0) {
        float t = 0.f;
#pragma unroll
        for (int w = 0; w < 16; ++w) t += red[w];
        out[0] = t / (float)n;
    }
}

extern "C" void kernel_launch(void* const* d_in, const int* in_sizes, int n_in,
                              void* d_out, int out_size, void* d_ws, size_t ws_size,
                              hipStream_t stream) {
    const float* P = (const float*)d_in[0];
    const int* y   = (const int*)d_in[1];
    float* out     = (float*)d_out;
    const int n = in_sizes[1];  // 8192

    // ws: Pn bf16 [n*256] | Aacc f32 [n] | Bacc f32 [n] | colPart f32 [1056*512]
    unsigned short* Pn = (unsigned short*)d_ws;
    float* Aacc = (float*)((char*)d_ws + (size_t)n * NF * 2);
    float* Bacc = Aacc + n;
    float* colPart = Bacc + n;

    const int ng = n / 256;  // col groups of 256
    k_prep<<<n / 4, 256, 0, stream>>>(P, Pn, Aacc);
    k_main<<<ng * (ng + 1), 256, 0, stream>>>(Pn, y, Aacc, Bacc, colPart);
    k_reduce<<<n / 256, 256, 0, stream>>>(colPart, Aacc, Bacc);
    k_final<<<1, 1024, 0, stream>>>(Aacc, Bacc, y, out, n);
}

// Round 3
// 159.845 us; speedup vs baseline: 1.0028x; 1.0028x over previous
//
#include <hip/hip_runtime.h>
#include <hip/hip_bf16.h>

// n=8192 rows, d=256 feat, 10 classes.
// loss = mean_i log1p(exp(0.5/0.7) * A_i * B_i)
//   A_i = sum_{j: y_j!=y_i} exp(sim_ij/0.7), B_i = sum_{j!=i: y_j==y_i} exp(-sim_ij/0.7)
//   sim = rownorm(P) @ rownorm(P)^T
//
// R10: R8/R9's single-pass epilogue (ca/cbv + in-loop shfl + LDS atomics) blew
// the ~168-reg/thread budget at (256,3) -> scratch spills = phantom ~60MB
// WRITE_SIZE (R9 removed the col atomics yet write stayed 64MB -> spills, not
// atomics). Fix: two-pass epilogue. Pass 1 = R7's row-side update verbatim
// (proven spill-free live set). Pass 2 (colacc only) RECOMPUTES e from the
// still-live acc tile (32 exp2/chunk, ~4cy each on trans pipe << spill cost)
// and accumulates col partials into WAVE-PRIVATE LDS slices (plain RMW, no
// CAS-loop atomics; +8KB LDS -> 41KB, still 3 blocks/CU). Partials dumped to
// private colPart[bid] (R9's k_reduce unchanged, race-free).

#define NF 256
#define TINV (1.0f / 0.7f)
#define SC2 2.0609929398439434f  // (1/0.7)*log2(e)

typedef __attribute__((ext_vector_type(8))) short short8;
typedef __attribute__((ext_vector_type(4))) float float4v;

typedef const __attribute__((address_space(1))) unsigned int glb_u32;
typedef __attribute__((address_space(3))) unsigned int lds_u32;

// One wave per row: normalize to bf16. Also zeroes the accumulators.
__global__ __launch_bounds__(256)
void k_prep(const float* __restrict__ P, unsigned short* __restrict__ Pn,
            float* __restrict__ AB) {  // AB = Aacc||Bacc, 2n floats
    int wave = threadIdx.x >> 6, lane = threadIdx.x & 63;
    int row = blockIdx.x * 4 + wave;
    if (threadIdx.x < 8) AB[blockIdx.x * 8 + threadIdx.x] = 0.f;
    float4 v = *(const float4*)(P + (size_t)row * NF + lane * 4);
    float sq = v.x * v.x + v.y * v.y + v.z * v.z + v.w * v.w;
#pragma unroll
    for (int off = 32; off; off >>= 1) sq += __shfl_xor(sq, off, 64);
    float r = rsqrtf(sq);
    __hip_bfloat16 h0 = __float2bfloat16(v.x * r), h1 = __float2bfloat16(v.y * r),
                   h2 = __float2bfloat16(v.z * r), h3 = __float2bfloat16(v.w * r);
    ushort4 o = { *(unsigned short*)&h0, *(unsigned short*)&h1,
                  *(unsigned short*)&h2, *(unsigned short*)&h3 };
    *(ushort4*)(Pn + (size_t)row * NF + lane * 4) = o;
}

__global__ __launch_bounds__(256, 3)
void k_main(const unsigned short* __restrict__ Pn, const int* __restrict__ y,
            float* __restrict__ Aacc, float* __restrict__ Bacc,
            float* __restrict__ colPart) {
    // B chunk: 64 cols x K=256, kc-major: ushort addr = kc*512 + col*8
    __shared__ __align__(16) unsigned short Bs[64 * NF];
    __shared__ int yc[256];
    __shared__ float colA[1024], colB[1024];  // wave-private slices [wave][256]

    const int tid = threadIdx.x;
    // Decode (I, C): cumulative blocks before group C is C*(C+1).
    int bid = blockIdx.x;
    int C = (int)((sqrtf(4.0f * (float)bid + 1.0f) - 1.0f) * 0.5f);
    while (C * (C + 1) > bid) --C;
    while ((C + 1) * (C + 2) <= bid) ++C;
    const int I = bid - C * (C + 1);          // row panel, I in [0, 2C+2)
    const int rb = I * 128, cb0 = C * 256;
    const bool colacc = (C > (I >> 1));       // uniform: col panels strictly above row panel

    const int lane = tid & 63, wave = tid >> 6;
    const int quad = lane >> 4, l15 = lane & 15;

    // DMA one 64-col chunk: 32 instrs (8 per wave), lane L -> col L.
    // kc-instr: lane L reads Pn[(cb0+c*64+L)*NF + kc*8], lands at kc*1024+L*16 B.
#define DMA_CHUNK(c)                                                          \
    {                                                                         \
        _Pragma("unroll")                                                     \
        for (int i = 0; i < 8; ++i) {                                         \
            const int kc = wave * 8 + i;                                      \
            const unsigned short* src =                                       \
                Pn + (size_t)(cb0 + (c) * 64 + lane) * NF + kc * 8;           \
            __builtin_amdgcn_global_load_lds((glb_u32*)src,                   \
                (lds_u32*)&Bs[kc * 512], 16, 0, 0);                           \
        }                                                                     \
    }

    DMA_CHUNK(0)   // issue first so DMA latency overlaps A-frag loads

    yc[tid] = y[cb0 + tid];
#pragma unroll
    for (int w = 0; w < 4; ++w) {
        colA[w * 256 + tid] = 0.f;
        colB[w * 256 + tid] = 0.f;
    }

    // A-frags: this wave's 32 rows x full K. m=l15, k=quad*8+j (16x16x32).
    const unsigned short* pa = Pn + (size_t)(rb + wave * 32 + l15) * NF + quad * 8;
    short8 afr[2][8];
#pragma unroll
    for (int tr = 0; tr < 2; ++tr)
#pragma unroll
        for (int ks = 0; ks < 8; ++ks)
            afr[tr][ks] = *(const short8*)(pa + (size_t)tr * 16 * NF + ks * 32);

    // Row classes byte-packed (rows tr*16 + quad*4 + r).
    unsigned yis[2];
#pragma unroll
    for (int tr = 0; tr < 2; ++tr) {
        int4 v = *(const int4*)(y + rb + wave * 32 + tr * 16 + quad * 4);
        yis[tr] = (unsigned)(v.x & 255) | ((unsigned)(v.y & 255) << 8) |
                  ((unsigned)(v.z & 255) << 16) | ((unsigned)(v.w & 255) << 24);
    }

    float rA[2][4], rB[2][4];
#pragma unroll
    for (int tr = 0; tr < 2; ++tr)
#pragma unroll
        for (int r = 0; r < 4; ++r) { rA[tr][r] = 0.f; rB[tr][r] = 0.f; }

#pragma unroll 1
    for (int c = 0; c < 4; ++c) {
        __syncthreads();   // own-vmcnt drained by compiler before barrier -> Bs ready

        float4v acc[2][4];
#pragma unroll
        for (int a = 0; a < 2; ++a)
#pragma unroll
            for (int b = 0; b < 4; ++b) acc[a][b] = (float4v){0.f, 0.f, 0.f, 0.f};

#pragma unroll
        for (int ks = 0; ks < 8; ++ks) {
            short8 fb[4];
#pragma unroll
            for (int tc = 0; tc < 4; ++tc)
                fb[tc] = *(const short8*)&Bs[(ks * 4 + quad) * 512 + (tc * 16 + l15) * 8];
#pragma unroll
            for (int tr = 0; tr < 2; ++tr)
#pragma unroll
                for (int tc = 0; tc < 4; ++tc)
                    acc[tr][tc] = __builtin_amdgcn_mfma_f32_16x16x32_bf16(
                        afr[tr][ks], fb[tc], acc[tr][tc], 0, 0, 0);
        }
        __syncthreads();   // all waves done reading Bs
        if (c < 3) DMA_CHUNK(c + 1)

        // ---- Pass 1: row-side (R7 epilogue verbatim). C/D: col=l15, row=quad*4+reg.
#pragma unroll
        for (int tc = 0; tc < 4; ++tc) {
            const int jl = c * 64 + tc * 16 + l15;
            const int yj = yc[jl];
            const int gj = cb0 + jl;
#pragma unroll
            for (int tr = 0; tr < 2; ++tr) {
                const int gi0 = rb + wave * 32 + tr * 16 + quad * 4;
#pragma unroll
                for (int r = 0; r < 4; ++r) {
                    const float s = acc[tr][tc][r];
                    const int cls = (yis[tr] >> (8 * r)) & 255;
                    const bool same = (cls == yj);
                    const float e = exp2f(s * (same ? -SC2 : SC2));
                    rA[tr][r] += same ? 0.f : e;
                    rB[tr][r] += (same && (gi0 + r != gj)) ? e : 0.f;
                }
            }
        }

        // ---- Pass 2: col-side (colacc blocks only; diagonal never present).
        // Recompute e from the still-live acc tile; minimal extra live state.
        if (colacc) {
#pragma unroll
            for (int tc = 0; tc < 4; ++tc) {
                const int jl = c * 64 + tc * 16 + l15;
                const int yj = yc[jl];
                float ca = 0.f, cb = 0.f;
#pragma unroll
                for (int tr = 0; tr < 2; ++tr)
#pragma unroll
                    for (int r = 0; r < 4; ++r) {
                        const float s = acc[tr][tc][r];
                        const int cls = (yis[tr] >> (8 * r)) & 255;
                        const bool same = (cls == yj);
                        const float e = exp2f(s * (same ? -SC2 : SC2));
                        ca += same ? 0.f : e;
                        cb += same ? e : 0.f;
                    }
                ca += __shfl_xor(ca, 16, 64); ca += __shfl_xor(ca, 32, 64);
                cb += __shfl_xor(cb, 16, 64); cb += __shfl_xor(cb, 32, 64);
                if (quad == 0) {               // lanes 0-15: distinct jl, wave-private slice
                    colA[wave * 256 + jl] += ca;
                    colB[wave * 256 + jl] += cb;
                }
            }
        }
    }

    // Row side: butterfly over 16 col-lanes; quad leaders issue atomics.
#pragma unroll
    for (int tr = 0; tr < 2; ++tr)
#pragma unroll
        for (int r = 0; r < 4; ++r) {
#pragma unroll
            for (int off = 1; off < 16; off <<= 1) {
                rA[tr][r] += __shfl_xor(rA[tr][r], off, 64);
                rB[tr][r] += __shfl_xor(rB[tr][r], off, 64);
            }
        }
    if (l15 == 0) {
#pragma unroll
        for (int tr = 0; tr < 2; ++tr)
#pragma unroll
            for (int r = 0; r < 4; ++r) {
                const int gi = rb + wave * 32 + tr * 16 + quad * 4 + r;
                atomicAdd(&Aacc[gi], rA[tr][r]);
                atomicAdd(&Bacc[gi], rB[tr][r]);
            }
    }

    // Column side: sum wave-private slices, dump to private per-block slot.
    if (colacc) {
        __syncthreads();
        float* cp = colPart + (size_t)bid * 512;
        cp[tid]       = colA[tid] + colA[256 + tid] + colA[512 + tid] + colA[768 + tid];
        cp[256 + tid] = colB[tid] + colB[256 + tid] + colB[512 + tid] + colB[768 + tid];
    }
}

// Sum per-block column partials into Aacc/Bacc. One thread per column.
// Group C's colacc blocks are bid = C*(C+1)+I for I in [0, 2C). Runs after
// k_main, so plain read-modify-write is race-free.
__global__ __launch_bounds__(256)
void k_reduce(const float* __restrict__ colPart, float* __restrict__ Aacc,
              float* __restrict__ Bacc) {
    const int j = blockIdx.x * 256 + threadIdx.x;  // column 0..8191
    const int C = j >> 8, o = j & 255;
    const float* p = colPart + (size_t)(C * (C + 1)) * 512 + o;
    float sA = 0.f, sB = 0.f;
    for (int I = 0; I < 2 * C; ++I) {
        sA += p[0];
        sB += p[256];
        p += 512;
    }
    Aacc[j] += sA;
    Bacc[j] += sB;
}

// Single block: ballot-based class histogram, mean loss, direct write of out[0].
__global__ __launch_bounds__(1024)
void k_final(const float* __restrict__ Aacc, const float* __restrict__ Bacc,
             const int* __restrict__ y, float* __restrict__ out, int n) {
    __shared__ int hist[16];
    __shared__ float red[16];
    const int tid = threadIdx.x;
    if (tid < 16) hist[tid] = 0;
    __syncthreads();
    int loc[10];
#pragma unroll
    for (int cc = 0; cc < 10; ++cc) loc[cc] = 0;
    for (int i = tid; i < n; i += 1024) {
        const int yv = y[i];
#pragma unroll
        for (int cc = 0; cc < 10; ++cc) {
            unsigned long long m = __ballot(yv == cc);
            if ((tid & 63) == 0) loc[cc] += __popcll(m);
        }
    }
    if ((tid & 63) == 0)
#pragma unroll
        for (int cc = 0; cc < 10; ++cc) atomicAdd(&hist[cc], loc[cc]);
    __syncthreads();
    const float M = __expf(0.5f * TINV);
    float s = 0.f;
    for (int i = tid; i < n; i += 1024) {
        const int cc = hist[y[i] & 15];
        const float a = (n - cc) > 0 ? Aacc[i] : 1.0f;
        const float b = (cc - 1) > 0 ? Bacc[i] : 1.0f;
        s += log1pf(M * a * b);
    }
#pragma unroll
    for (int off = 32; off; off >>= 1) s += __shfl_xor(s, off, 64);
    if ((tid & 63) == 0) red[tid >> 6] = s;
    __syncthreads();
    if (tid == 0) {
        float t = 0.f;
#pragma unroll
        for (int w = 0; w < 16; ++w) t += red[w];
        out[0] = t / (float)n;
    }
}

extern "C" void kernel_launch(void* const* d_in, const int* in_sizes, int n_in,
                              void* d_out, int out_size, void* d_ws, size_t ws_size,
                              hipStream_t stream) {
    const float* P = (const float*)d_in[0];
    const int* y   = (const int*)d_in[1];
    float* out     = (float*)d_out;
    const int n = in_sizes[1];  // 8192

    // ws: Pn bf16 [n*256] | Aacc f32 [n] | Bacc f32 [n] | colPart f32 [1056*512]
    unsigned short* Pn = (unsigned short*)d_ws;
    float* Aacc = (float*)((char*)d_ws + (size_t)n * NF * 2);
    float* Bacc = Aacc + n;
    float* colPart = Bacc + n;

    const int ng = n / 256;  // col groups of 256
    k_prep<<<n / 4, 256, 0, stream>>>(P, Pn, Aacc);
    k_main<<<ng * (ng + 1), 256, 0, stream>>>(Pn, y, Aacc, Bacc, colPart);
    k_reduce<<<n / 256, 256, 0, stream>>>(colPart, Aacc, Bacc);
    k_final<<<1, 1024, 0, stream>>>(Aacc, Bacc, y, out, n);
}

// Round 4
// 141.632 us; speedup vs baseline: 1.1318x; 1.1286x over previous
//
#include <hip/hip_runtime.h>
#include <hip/hip_bf16.h>

// n=8192 rows, d=256 feat, 10 classes.
// loss = mean_i log1p(exp(0.5/0.7) * A_i * B_i)
//   A_i = sum_{j: y_j!=y_i} exp(sim_ij/0.7), B_i = sum_{j!=i: y_j==y_i} exp(-sim_ij/0.7)
//   sim = rownorm(P) @ rownorm(P)^T
//
// R11: differential evidence R9->R10 (epilogue-only restructure moved fabric
// WRITE 64->45MB) proves the phantom traffic is SCRATCH SPILLS: epilogue live
// set (afr 64 + acc 32 + rA/rB 16 + col temps, AGPRs unified) > the ~168-reg
// cap implied by __launch_bounds__(256,3). Write-heavy signature fits scratch
// (spill stores write back to fabric; fills hit L2). Achieved occupancy has
// been ~2 blocks/CU all along, so (256,3) bought nothing. Fix: (256,2) ->
// 256-reg cap, zero spills, same occupancy. Also 2x-parallelize k_reduce
// (2 threads/col, 64 blocks). Everything else identical to R10.

#define NF 256
#define TINV (1.0f / 0.7f)
#define SC2 2.0609929398439434f  // (1/0.7)*log2(e)

typedef __attribute__((ext_vector_type(8))) short short8;
typedef __attribute__((ext_vector_type(4))) float float4v;

typedef const __attribute__((address_space(1))) unsigned int glb_u32;
typedef __attribute__((address_space(3))) unsigned int lds_u32;

// One wave per row: normalize to bf16. Also zeroes the accumulators.
__global__ __launch_bounds__(256)
void k_prep(const float* __restrict__ P, unsigned short* __restrict__ Pn,
            float* __restrict__ AB) {  // AB = Aacc||Bacc, 2n floats
    int wave = threadIdx.x >> 6, lane = threadIdx.x & 63;
    int row = blockIdx.x * 4 + wave;
    if (threadIdx.x < 8) AB[blockIdx.x * 8 + threadIdx.x] = 0.f;
    float4 v = *(const float4*)(P + (size_t)row * NF + lane * 4);
    float sq = v.x * v.x + v.y * v.y + v.z * v.z + v.w * v.w;
#pragma unroll
    for (int off = 32; off; off >>= 1) sq += __shfl_xor(sq, off, 64);
    float r = rsqrtf(sq);
    __hip_bfloat16 h0 = __float2bfloat16(v.x * r), h1 = __float2bfloat16(v.y * r),
                   h2 = __float2bfloat16(v.z * r), h3 = __float2bfloat16(v.w * r);
    ushort4 o = { *(unsigned short*)&h0, *(unsigned short*)&h1,
                  *(unsigned short*)&h2, *(unsigned short*)&h3 };
    *(ushort4*)(Pn + (size_t)row * NF + lane * 4) = o;
}

__global__ __launch_bounds__(256, 2)
void k_main(const unsigned short* __restrict__ Pn, const int* __restrict__ y,
            float* __restrict__ Aacc, float* __restrict__ Bacc,
            float* __restrict__ colPart) {
    // B chunk: 64 cols x K=256, kc-major: ushort addr = kc*512 + col*8
    __shared__ __align__(16) unsigned short Bs[64 * NF];
    __shared__ int yc[256];
    __shared__ float colA[1024], colB[1024];  // wave-private slices [wave][256]

    const int tid = threadIdx.x;
    // Decode (I, C): cumulative blocks before group C is C*(C+1).
    int bid = blockIdx.x;
    int C = (int)((sqrtf(4.0f * (float)bid + 1.0f) - 1.0f) * 0.5f);
    while (C * (C + 1) > bid) --C;
    while ((C + 1) * (C + 2) <= bid) ++C;
    const int I = bid - C * (C + 1);          // row panel, I in [0, 2C+2)
    const int rb = I * 128, cb0 = C * 256;
    const bool colacc = (C > (I >> 1));       // uniform: col panels strictly above row panel

    const int lane = tid & 63, wave = tid >> 6;
    const int quad = lane >> 4, l15 = lane & 15;

    // DMA one 64-col chunk: 32 instrs (8 per wave), lane L -> col L.
    // kc-instr: lane L reads Pn[(cb0+c*64+L)*NF + kc*8], lands at kc*1024+L*16 B.
#define DMA_CHUNK(c)                                                          \
    {                                                                         \
        _Pragma("unroll")                                                     \
        for (int i = 0; i < 8; ++i) {                                         \
            const int kc = wave * 8 + i;                                      \
            const unsigned short* src =                                       \
                Pn + (size_t)(cb0 + (c) * 64 + lane) * NF + kc * 8;           \
            __builtin_amdgcn_global_load_lds((glb_u32*)src,                   \
                (lds_u32*)&Bs[kc * 512], 16, 0, 0);                           \
        }                                                                     \
    }

    DMA_CHUNK(0)   // issue first so DMA latency overlaps A-frag loads

    yc[tid] = y[cb0 + tid];
#pragma unroll
    for (int w = 0; w < 4; ++w) {
        colA[w * 256 + tid] = 0.f;
        colB[w * 256 + tid] = 0.f;
    }

    // A-frags: this wave's 32 rows x full K. m=l15, k=quad*8+j (16x16x32).
    const unsigned short* pa = Pn + (size_t)(rb + wave * 32 + l15) * NF + quad * 8;
    short8 afr[2][8];
#pragma unroll
    for (int tr = 0; tr < 2; ++tr)
#pragma unroll
        for (int ks = 0; ks < 8; ++ks)
            afr[tr][ks] = *(const short8*)(pa + (size_t)tr * 16 * NF + ks * 32);

    // Row classes byte-packed (rows tr*16 + quad*4 + r).
    unsigned yis[2];
#pragma unroll
    for (int tr = 0; tr < 2; ++tr) {
        int4 v = *(const int4*)(y + rb + wave * 32 + tr * 16 + quad * 4);
        yis[tr] = (unsigned)(v.x & 255) | ((unsigned)(v.y & 255) << 8) |
                  ((unsigned)(v.z & 255) << 16) | ((unsigned)(v.w & 255) << 24);
    }

    float rA[2][4], rB[2][4];
#pragma unroll
    for (int tr = 0; tr < 2; ++tr)
#pragma unroll
        for (int r = 0; r < 4; ++r) { rA[tr][r] = 0.f; rB[tr][r] = 0.f; }

#pragma unroll 1
    for (int c = 0; c < 4; ++c) {
        __syncthreads();   // own-vmcnt drained by compiler before barrier -> Bs ready

        float4v acc[2][4];
#pragma unroll
        for (int a = 0; a < 2; ++a)
#pragma unroll
            for (int b = 0; b < 4; ++b) acc[a][b] = (float4v){0.f, 0.f, 0.f, 0.f};

#pragma unroll
        for (int ks = 0; ks < 8; ++ks) {
            short8 fb[4];
#pragma unroll
            for (int tc = 0; tc < 4; ++tc)
                fb[tc] = *(const short8*)&Bs[(ks * 4 + quad) * 512 + (tc * 16 + l15) * 8];
#pragma unroll
            for (int tr = 0; tr < 2; ++tr)
#pragma unroll
                for (int tc = 0; tc < 4; ++tc)
                    acc[tr][tc] = __builtin_amdgcn_mfma_f32_16x16x32_bf16(
                        afr[tr][ks], fb[tc], acc[tr][tc], 0, 0, 0);
        }
        __syncthreads();   // all waves done reading Bs
        if (c < 3) DMA_CHUNK(c + 1)

        // ---- Pass 1: row-side (R7 epilogue verbatim). C/D: col=l15, row=quad*4+reg.
#pragma unroll
        for (int tc = 0; tc < 4; ++tc) {
            const int jl = c * 64 + tc * 16 + l15;
            const int yj = yc[jl];
            const int gj = cb0 + jl;
#pragma unroll
            for (int tr = 0; tr < 2; ++tr) {
                const int gi0 = rb + wave * 32 + tr * 16 + quad * 4;
#pragma unroll
                for (int r = 0; r < 4; ++r) {
                    const float s = acc[tr][tc][r];
                    const int cls = (yis[tr] >> (8 * r)) & 255;
                    const bool same = (cls == yj);
                    const float e = exp2f(s * (same ? -SC2 : SC2));
                    rA[tr][r] += same ? 0.f : e;
                    rB[tr][r] += (same && (gi0 + r != gj)) ? e : 0.f;
                }
            }
        }

        // ---- Pass 2: col-side (colacc blocks only; diagonal never present).
        // Recompute e from the still-live acc tile; minimal extra live state.
        if (colacc) {
#pragma unroll
            for (int tc = 0; tc < 4; ++tc) {
                const int jl = c * 64 + tc * 16 + l15;
                const int yj = yc[jl];
                float ca = 0.f, cb = 0.f;
#pragma unroll
                for (int tr = 0; tr < 2; ++tr)
#pragma unroll
                    for (int r = 0; r < 4; ++r) {
                        const float s = acc[tr][tc][r];
                        const int cls = (yis[tr] >> (8 * r)) & 255;
                        const bool same = (cls == yj);
                        const float e = exp2f(s * (same ? -SC2 : SC2));
                        ca += same ? 0.f : e;
                        cb += same ? e : 0.f;
                    }
                ca += __shfl_xor(ca, 16, 64); ca += __shfl_xor(ca, 32, 64);
                cb += __shfl_xor(cb, 16, 64); cb += __shfl_xor(cb, 32, 64);
                if (quad == 0) {               // lanes 0-15: distinct jl, wave-private slice
                    colA[wave * 256 + jl] += ca;
                    colB[wave * 256 + jl] += cb;
                }
            }
        }
    }

    // Row side: butterfly over 16 col-lanes; quad leaders issue atomics.
#pragma unroll
    for (int tr = 0; tr < 2; ++tr)
#pragma unroll
        for (int r = 0; r < 4; ++r) {
#pragma unroll
            for (int off = 1; off < 16; off <<= 1) {
                rA[tr][r] += __shfl_xor(rA[tr][r], off, 64);
                rB[tr][r] += __shfl_xor(rB[tr][r], off, 64);
            }
        }
    if (l15 == 0) {
#pragma unroll
        for (int tr = 0; tr < 2; ++tr)
#pragma unroll
            for (int r = 0; r < 4; ++r) {
                const int gi = rb + wave * 32 + tr * 16 + quad * 4 + r;
                atomicAdd(&Aacc[gi], rA[tr][r]);
                atomicAdd(&Bacc[gi], rB[tr][r]);
            }
    }

    // Column side: sum wave-private slices, dump to private per-block slot.
    if (colacc) {
        __syncthreads();
        float* cp = colPart + (size_t)bid * 512;
        cp[tid]       = colA[tid] + colA[256 + tid] + colA[512 + tid] + colA[768 + tid];
        cp[256 + tid] = colB[tid] + colB[256 + tid] + colB[512 + tid] + colB[768 + tid];
    }
}

// Sum per-block column partials into Aacc/Bacc. 2 threads per column
// (half = parity of I), shfl-combined. Group C's colacc blocks are
// bid = C*(C+1)+I for I in [0, 2C). Runs after k_main -> race-free.
__global__ __launch_bounds__(256)
void k_reduce(const float* __restrict__ colPart, float* __restrict__ Aacc,
              float* __restrict__ Bacc) {
    const int t = threadIdx.x;
    const int jloc = t >> 1, half = t & 1;
    const int j = blockIdx.x * 128 + jloc;   // column 0..8191
    const int C = j >> 8, o = j & 255;
    const float* p = colPart + (size_t)(C * (C + 1) + half) * 512 + o;
    float sA = 0.f, sB = 0.f;
    for (int I = half; I < 2 * C; I += 2) {
        sA += p[0];
        sB += p[256];
        p += 1024;
    }
    sA += __shfl_xor(sA, 1, 64);
    sB += __shfl_xor(sB, 1, 64);
    if (half == 0) {
        Aacc[j] += sA;
        Bacc[j] += sB;
    }
}

// Single block: ballot-based class histogram, mean loss, direct write of out[0].
__global__ __launch_bounds__(1024)
void k_final(const float* __restrict__ Aacc, const float* __restrict__ Bacc,
             const int* __restrict__ y, float* __restrict__ out, int n) {
    __shared__ int hist[16];
    __shared__ float red[16];
    const int tid = threadIdx.x;
    if (tid < 16) hist[tid] = 0;
    __syncthreads();
    int loc[10];
#pragma unroll
    for (int cc = 0; cc < 10; ++cc) loc[cc] = 0;
    for (int i = tid; i < n; i += 1024) {
        const int yv = y[i];
#pragma unroll
        for (int cc = 0; cc < 10; ++cc) {
            unsigned long long m = __ballot(yv == cc);
            if ((tid & 63) == 0) loc[cc] += __popcll(m);
        }
    }
    if ((tid & 63) == 0)
#pragma unroll
        for (int cc = 0; cc < 10; ++cc) atomicAdd(&hist[cc], loc[cc]);
    __syncthreads();
    const float M = __expf(0.5f * TINV);
    float s = 0.f;
    for (int i = tid; i < n; i += 1024) {
        const int cc = hist[y[i] & 15];
        const float a = (n - cc) > 0 ? Aacc[i] : 1.0f;
        const float b = (cc - 1) > 0 ? Bacc[i] : 1.0f;
        s += log1pf(M * a * b);
    }
#pragma unroll
    for (int off = 32; off; off >>= 1) s += __shfl_xor(s, off, 64);
    if ((tid & 63) == 0) red[tid >> 6] = s;
    __syncthreads();
    if (tid == 0) {
        float t = 0.f;
#pragma unroll
        for (int w = 0; w < 16; ++w) t += red[w];
        out[0] = t / (float)n;
    }
}

extern "C" void kernel_launch(void* const* d_in, const int* in_sizes, int n_in,
                              void* d_out, int out_size, void* d_ws, size_t ws_size,
                              hipStream_t stream) {
    const float* P = (const float*)d_in[0];
    const int* y   = (const int*)d_in[1];
    float* out     = (float*)d_out;
    const int n = in_sizes[1];  // 8192

    // ws: Pn bf16 [n*256] | Aacc f32 [n] | Bacc f32 [n] | colPart f32 [1056*512]
    unsigned short* Pn = (unsigned short*)d_ws;
    float* Aacc = (float*)((char*)d_ws + (size_t)n * NF * 2);
    float* Bacc = Aacc + n;
    float* colPart = Bacc + n;

    const int ng = n / 256;  // col groups of 256
    k_prep<<<n / 4, 256, 0, stream>>>(P, Pn, Aacc);
    k_main<<<ng * (ng + 1), 256, 0, stream>>>(Pn, y, Aacc, Bacc, colPart);
    k_reduce<<<n / 128, 256, 0, stream>>>(colPart, Aacc, Bacc);
    k_final<<<1, 1024, 0, stream>>>(Aacc, Bacc, y, out, n);
}

// Round 5
// 141.580 us; speedup vs baseline: 1.1322x; 1.0004x over previous
//
#include <hip/hip_runtime.h>
#include <hip/hip_bf16.h>

// n=8192 rows, d=256 feat, 10 classes.
// loss = mean_i log1p(exp(0.5/0.7) * A_i * B_i)
//   A_i = sum_{j: y_j!=y_i} exp(sim_ij/0.7), B_i = sum_{j!=i: y_j==y_i} exp(-sim_ij/0.7)
//   sim = rownorm(P) @ rownorm(P)^T
//
// R12: R11 fixed the spills (write 45->6MB) but per-tile cost stayed 1.85x R7:
// (a) two-pass epilogue doubled exp2/selects, (b) 1056-block grid at ~3/CU has
// a 31% tail, (c) 4th launch ~9us. Fixes, same math: triangle grid over
// 128x128 panel pairs (I<=C2, 2080 blocks, 2 chunks of 64 cols each; diagonal
// blocks row-only+diag-check, off-diag blocks FUSED row+col epilogue computing
// e once -- no diag check needed, ranges disjoint); col partials via native
// LDS ds_add_f32 into shared colA/colB[128]; k_reduce+k_final merged into
// k_tail (per-block ballot hist + partial reduce + atomicAdd loss).

#define NF 256
#define TINV (1.0f / 0.7f)
#define SC2 2.0609929398439434f  // (1/0.7)*log2(e)

typedef __attribute__((ext_vector_type(8))) short short8;
typedef __attribute__((ext_vector_type(4))) float float4v;

typedef const __attribute__((address_space(1))) unsigned int glb_u32;
typedef __attribute__((address_space(3))) unsigned int lds_u32;

// One wave per row: normalize to bf16. Also zeroes accumulators and out.
__global__ __launch_bounds__(256)
void k_prep(const float* __restrict__ P, unsigned short* __restrict__ Pn,
            float* __restrict__ AB, float* __restrict__ out) {
    int wave = threadIdx.x >> 6, lane = threadIdx.x & 63;
    int row = blockIdx.x * 4 + wave;
    if (threadIdx.x < 8) AB[blockIdx.x * 8 + threadIdx.x] = 0.f;
    if (blockIdx.x == 0 && threadIdx.x == 0) out[0] = 0.f;
    float4 v = *(const float4*)(P + (size_t)row * NF + lane * 4);
    float sq = v.x * v.x + v.y * v.y + v.z * v.z + v.w * v.w;
#pragma unroll
    for (int off = 32; off; off >>= 1) sq += __shfl_xor(sq, off, 64);
    float r = rsqrtf(sq);
    __hip_bfloat16 h0 = __float2bfloat16(v.x * r), h1 = __float2bfloat16(v.y * r),
                   h2 = __float2bfloat16(v.z * r), h3 = __float2bfloat16(v.w * r);
    ushort4 o = { *(unsigned short*)&h0, *(unsigned short*)&h1,
                  *(unsigned short*)&h2, *(unsigned short*)&h3 };
    *(ushort4*)(Pn + (size_t)row * NF + lane * 4) = o;
}

__global__ __launch_bounds__(256, 2)
void k_main(const unsigned short* __restrict__ Pn, const int* __restrict__ y,
            float* __restrict__ Aacc, float* __restrict__ Bacc,
            float* __restrict__ colPart) {
    // B chunk: 64 cols x K=256, kc-major: ushort addr = kc*512 + col*8
    __shared__ __align__(16) unsigned short Bs[64 * NF];
    __shared__ int yc[128];
    __shared__ float colA[128], colB[128];

    const int tid = threadIdx.x;
    // Decode (I, C2): bid = C2*(C2+1)/2 + I, I in [0, C2].
    int bid = blockIdx.x;
    int C2 = (int)((sqrtf(8.0f * (float)bid + 1.0f) - 1.0f) * 0.5f);
    while ((C2 * (C2 + 1)) / 2 > bid) --C2;
    while (((C2 + 1) * (C2 + 2)) / 2 <= bid) ++C2;
    const int I = bid - (C2 * (C2 + 1)) / 2;
    const int rb = I * 128, cb0 = C2 * 128;
    const bool offdiag = (I < C2);   // uniform: fused row+col, no diag overlap

    const int lane = tid & 63, wave = tid >> 6;
    const int quad = lane >> 4, l15 = lane & 15;

    // DMA one 64-col chunk: 32 instrs (8 per wave), lane L -> col L.
#define DMA_CHUNK(c)                                                          \
    {                                                                         \
        _Pragma("unroll")                                                     \
        for (int i = 0; i < 8; ++i) {                                         \
            const int kc = wave * 8 + i;                                      \
            const unsigned short* src =                                       \
                Pn + (size_t)(cb0 + (c) * 64 + lane) * NF + kc * 8;           \
            __builtin_amdgcn_global_load_lds((glb_u32*)src,                   \
                (lds_u32*)&Bs[kc * 512], 16, 0, 0);                           \
        }                                                                     \
    }

    DMA_CHUNK(0)   // issue first so DMA latency overlaps A-frag loads

    if (tid < 128) {
        yc[tid] = y[cb0 + tid];
        colA[tid] = 0.f;
        colB[tid] = 0.f;
    }

    // A-frags: this wave's 32 rows x full K. m=l15, k=quad*8+j (16x16x32).
    const unsigned short* pa = Pn + (size_t)(rb + wave * 32 + l15) * NF + quad * 8;
    short8 afr[2][8];
#pragma unroll
    for (int tr = 0; tr < 2; ++tr)
#pragma unroll
        for (int ks = 0; ks < 8; ++ks)
            afr[tr][ks] = *(const short8*)(pa + (size_t)tr * 16 * NF + ks * 32);

    // Row classes byte-packed (rows tr*16 + quad*4 + r).
    unsigned yis[2];
#pragma unroll
    for (int tr = 0; tr < 2; ++tr) {
        int4 v = *(const int4*)(y + rb + wave * 32 + tr * 16 + quad * 4);
        yis[tr] = (unsigned)(v.x & 255) | ((unsigned)(v.y & 255) << 8) |
                  ((unsigned)(v.z & 255) << 16) | ((unsigned)(v.w & 255) << 24);
    }

    float rA[2][4], rB[2][4];
#pragma unroll
    for (int tr = 0; tr < 2; ++tr)
#pragma unroll
        for (int r = 0; r < 4; ++r) { rA[tr][r] = 0.f; rB[tr][r] = 0.f; }

#pragma unroll 1
    for (int c = 0; c < 2; ++c) {
        __syncthreads();   // own-vmcnt drained by compiler before barrier -> Bs ready

        float4v acc[2][4];
#pragma unroll
        for (int a = 0; a < 2; ++a)
#pragma unroll
            for (int b = 0; b < 4; ++b) acc[a][b] = (float4v){0.f, 0.f, 0.f, 0.f};

#pragma unroll
        for (int ks = 0; ks < 8; ++ks) {
            short8 fb[4];
#pragma unroll
            for (int tc = 0; tc < 4; ++tc)
                fb[tc] = *(const short8*)&Bs[(ks * 4 + quad) * 512 + (tc * 16 + l15) * 8];
#pragma unroll
            for (int tr = 0; tr < 2; ++tr)
#pragma unroll
                for (int tc = 0; tc < 4; ++tc)
                    acc[tr][tc] = __builtin_amdgcn_mfma_f32_16x16x32_bf16(
                        afr[tr][ks], fb[tc], acc[tr][tc], 0, 0, 0);
        }
        __syncthreads();   // all waves done reading Bs
        if (c < 1) DMA_CHUNK(1)

        if (offdiag) {
            // Fused row+col epilogue; row/col ranges disjoint -> no diag check.
#pragma unroll
            for (int tc = 0; tc < 4; ++tc) {
                const int jl = c * 64 + tc * 16 + l15;
                const int yj = yc[jl];
                float ca = 0.f, cb = 0.f;
#pragma unroll
                for (int tr = 0; tr < 2; ++tr)
#pragma unroll
                    for (int r = 0; r < 4; ++r) {
                        const float s = acc[tr][tc][r];
                        const int cls = (yis[tr] >> (8 * r)) & 255;
                        const bool same = (cls == yj);
                        const float e = exp2f(s * (same ? -SC2 : SC2));
                        rA[tr][r] += same ? 0.f : e;
                        rB[tr][r] += same ? e : 0.f;
                        ca += same ? 0.f : e;
                        cb += same ? e : 0.f;
                    }
                ca += __shfl_xor(ca, 16, 64); ca += __shfl_xor(ca, 32, 64);
                cb += __shfl_xor(cb, 16, 64); cb += __shfl_xor(cb, 32, 64);
                if (quad == 0) {   // 16 lanes, distinct jl -> native ds_add_f32
                    atomicAdd(&colA[jl], ca);
                    atomicAdd(&colB[jl], cb);
                }
            }
        } else {
            // Diagonal block: row-only, with self-exclusion check.
#pragma unroll
            for (int tc = 0; tc < 4; ++tc) {
                const int jl = c * 64 + tc * 16 + l15;
                const int yj = yc[jl];
                const int gj = cb0 + jl;
#pragma unroll
                for (int tr = 0; tr < 2; ++tr) {
                    const int gi0 = rb + wave * 32 + tr * 16 + quad * 4;
#pragma unroll
                    for (int r = 0; r < 4; ++r) {
                        const float s = acc[tr][tc][r];
                        const int cls = (yis[tr] >> (8 * r)) & 255;
                        const bool same = (cls == yj);
                        const float e = exp2f(s * (same ? -SC2 : SC2));
                        rA[tr][r] += same ? 0.f : e;
                        rB[tr][r] += (same && (gi0 + r != gj)) ? e : 0.f;
                    }
                }
            }
        }
    }

    // Row side: butterfly over 16 col-lanes; quad leaders issue atomics.
#pragma unroll
    for (int tr = 0; tr < 2; ++tr)
#pragma unroll
        for (int r = 0; r < 4; ++r) {
#pragma unroll
            for (int off = 1; off < 16; off <<= 1) {
                rA[tr][r] += __shfl_xor(rA[tr][r], off, 64);
                rB[tr][r] += __shfl_xor(rB[tr][r], off, 64);
            }
        }
    if (l15 == 0) {
#pragma unroll
        for (int tr = 0; tr < 2; ++tr)
#pragma unroll
            for (int r = 0; r < 4; ++r) {
                const int gi = rb + wave * 32 + tr * 16 + quad * 4 + r;
                atomicAdd(&Aacc[gi], rA[tr][r]);
                atomicAdd(&Bacc[gi], rB[tr][r]);
            }
    }

    // Column side: dump 128 A + 128 B partials to private slot (coalesced).
    if (offdiag) {
        __syncthreads();
        float* cp = colPart + (size_t)bid * 256;
        cp[tid] = (tid < 128) ? colA[tid] : colB[tid - 128];
    }
}

// Fused reduce+final: per-block ballot hist, column-partial reduce
// (2 threads/col), per-row loss, one atomicAdd into out per block.
// Group C2's col partials live at bid = C2*(C2+1)/2 + I for I in [0, C2).
__global__ __launch_bounds__(256)
void k_tail(const float* __restrict__ colPart, const float* __restrict__ Aacc,
            const float* __restrict__ Bacc, const int* __restrict__ y,
            float* __restrict__ out, int n) {
    __shared__ int hist[16];
    __shared__ float red[4];
    const int tid = threadIdx.x;
    if (tid < 16) hist[tid] = 0;
    __syncthreads();
    int loc[10];
#pragma unroll
    for (int cc = 0; cc < 10; ++cc) loc[cc] = 0;
    for (int i = tid; i < n; i += 256) {
        const int yv = y[i];
#pragma unroll
        for (int cc = 0; cc < 10; ++cc) {
            unsigned long long m = __ballot(yv == cc);
            if ((tid & 63) == 0) loc[cc] += __popcll(m);
        }
    }
    if ((tid & 63) == 0)
#pragma unroll
        for (int cc = 0; cc < 10; ++cc) atomicAdd(&hist[cc], loc[cc]);
    __syncthreads();

    const int jloc = tid >> 1, half = tid & 1;
    const int j = blockIdx.x * 128 + jloc;   // column/row 0..8191
    const int C2 = j >> 7, o = j & 127;
    const float* p = colPart + ((size_t)(C2 * (C2 + 1)) / 2 + half) * 256 + o;
    float sA = 0.f, sB = 0.f;
    for (int I = half; I < C2; I += 2) {
        sA += p[0];
        sB += p[128];
        p += 512;
    }
    sA += __shfl_xor(sA, 1, 64);
    sB += __shfl_xor(sB, 1, 64);

    float term = 0.f;
    if (half == 0) {
        const float M = __expf(0.5f * TINV);
        const int cc = hist[y[j] & 15];
        float a = Aacc[j] + sA;
        float b = Bacc[j] + sB;
        a = (n - cc) > 0 ? a : 1.0f;
        b = (cc - 1) > 0 ? b : 1.0f;
        term = log1pf(M * a * b);
    }
#pragma unroll
    for (int off = 32; off; off >>= 1) term += __shfl_xor(term, off, 64);
    if ((tid & 63) == 0) red[tid >> 6] = term;
    __syncthreads();
    if (tid == 0)
        atomicAdd(out, (red[0] + red[1] + red[2] + red[3]) / (float)n);
}

extern "C" void kernel_launch(void* const* d_in, const int* in_sizes, int n_in,
                              void* d_out, int out_size, void* d_ws, size_t ws_size,
                              hipStream_t stream) {
    const float* P = (const float*)d_in[0];
    const int* y   = (const int*)d_in[1];
    float* out     = (float*)d_out;
    const int n = in_sizes[1];  // 8192

    // ws: Pn bf16 [n*256] | Aacc f32 [n] | Bacc f32 [n] | colPart f32 [2080*256]
    unsigned short* Pn = (unsigned short*)d_ws;
    float* Aacc = (float*)((char*)d_ws + (size_t)n * NF * 2);
    float* Bacc = Aacc + n;
    float* colPart = Bacc + n;

    const int np = n / 128;                 // 64 panels of 128
    const int nblk = np * (np + 1) / 2;     // 2080 triangle blocks
    k_prep<<<n / 4, 256, 0, stream>>>(P, Pn, Aacc, out);
    k_main<<<nblk, 256, 0, stream>>>(Pn, y, Aacc, Bacc, colPart);
    k_tail<<<n / 128, 256, 0, stream>>>(colPart, Aacc, Bacc, y, out, n);
}

// Round 6
// 139.004 us; speedup vs baseline: 1.1532x; 1.0185x over previous
//
#include <hip/hip_runtime.h>
#include <hip/hip_bf16.h>

// n=8192 rows, d=256 feat, 10 classes.
// loss = mean_i log1p(exp(0.5/0.7) * A_i * B_i)
//   A_i = sum_{j: y_j!=y_i} exp(sim_ij/0.7), B_i = sum_{j!=i: y_j==y_i} exp(-sim_ij/0.7)
//   sim = rownorm(P) @ rownorm(P)^T
//
// R13: R7/R11/R12 wall time (~67-70us) was invariant to halving compute ->
// floor = exposed latency under weak concurrency (8 waves/CU, barrier-chained
// phases; busy counters sum to ~25% of wall). Fix, same triangle math:
// (1) 512-thread blocks, 8 waves x 16 rows -> live set ~90 regs, cap 128 via
// __launch_bounds__(512,4) -> 16 waves/CU (2x). (2) BOTH 64-col B-chunks
// DMA'd up front into Bs[2] (64KB LDS dbuf, 66KB total, 2 blocks/CU) -> ONE
// barrier before compute (own-vmcnt drain at barrier publishes all DMA),
// one before colPart dump. No mid-block phase barriers; waves free-run.
// Triangle grid over 128x128 panel pairs (I<=C2), 2080 blocks: diag blocks
// row-only+self-exclusion (zero waste), offdiag fused row+col epilogue.

#define NF 256
#define TINV (1.0f / 0.7f)
#define SC2 2.0609929398439434f  // (1/0.7)*log2(e)

typedef __attribute__((ext_vector_type(8))) short short8;
typedef __attribute__((ext_vector_type(4))) float float4v;

typedef const __attribute__((address_space(1))) unsigned int glb_u32;
typedef __attribute__((address_space(3))) unsigned int lds_u32;

// One wave per row: normalize to bf16. Also zeroes accumulators and out.
__global__ __launch_bounds__(256)
void k_prep(const float* __restrict__ P, unsigned short* __restrict__ Pn,
            float* __restrict__ AB, float* __restrict__ out) {
    int wave = threadIdx.x >> 6, lane = threadIdx.x & 63;
    int row = blockIdx.x * 4 + wave;
    if (threadIdx.x < 8) AB[blockIdx.x * 8 + threadIdx.x] = 0.f;
    if (blockIdx.x == 0 && threadIdx.x == 0) out[0] = 0.f;
    float4 v = *(const float4*)(P + (size_t)row * NF + lane * 4);
    float sq = v.x * v.x + v.y * v.y + v.z * v.z + v.w * v.w;
#pragma unroll
    for (int off = 32; off; off >>= 1) sq += __shfl_xor(sq, off, 64);
    float r = rsqrtf(sq);
    __hip_bfloat16 h0 = __float2bfloat16(v.x * r), h1 = __float2bfloat16(v.y * r),
                   h2 = __float2bfloat16(v.z * r), h3 = __float2bfloat16(v.w * r);
    ushort4 o = { *(unsigned short*)&h0, *(unsigned short*)&h1,
                  *(unsigned short*)&h2, *(unsigned short*)&h3 };
    *(ushort4*)(Pn + (size_t)row * NF + lane * 4) = o;
}

__global__ __launch_bounds__(512, 4)
void k_main(const unsigned short* __restrict__ Pn, const int* __restrict__ y,
            float* __restrict__ Aacc, float* __restrict__ Bacc,
            float* __restrict__ colPart) {
    // Two B chunks resident: chunk c = 64 cols x K=256, kc-major:
    // ushort addr = kc*512 + col*8, kc in [0,32) (8 k's each).
    __shared__ __align__(16) unsigned short Bs[2][32 * 512];
    __shared__ int yc[128];
    __shared__ float colA[128], colB[128];

    const int tid = threadIdx.x;
    // Decode (I, C2): bid = C2*(C2+1)/2 + I, I in [0, C2].
    int bid = blockIdx.x;
    int C2 = (int)((sqrtf(8.0f * (float)bid + 1.0f) - 1.0f) * 0.5f);
    while ((C2 * (C2 + 1)) / 2 > bid) --C2;
    while (((C2 + 1) * (C2 + 2)) / 2 <= bid) ++C2;
    const int I = bid - (C2 * (C2 + 1)) / 2;
    const int rb = I * 128, cb0 = C2 * 128;
    const bool offdiag = (I < C2);   // uniform

    const int lane = tid & 63, wave = tid >> 6;   // 8 waves
    const int quad = lane >> 4, l15 = lane & 15;

    // DMA one 64-col chunk: 32 instrs (4 per wave), lane L -> col L.
#define DMA_CHUNK(c)                                                          \
    {                                                                         \
        _Pragma("unroll")                                                     \
        for (int i = 0; i < 4; ++i) {                                         \
            const int kc = wave * 4 + i;                                      \
            const unsigned short* src =                                       \
                Pn + (size_t)(cb0 + (c) * 64 + lane) * NF + kc * 8;           \
            __builtin_amdgcn_global_load_lds((glb_u32*)src,                   \
                (lds_u32*)&Bs[c][kc * 512], 16, 0, 0);                        \
        }                                                                     \
    }

    DMA_CHUNK(0)
    DMA_CHUNK(1)

    if (tid < 128) {
        yc[tid] = y[cb0 + tid];
        colA[tid] = 0.f;
        colB[tid] = 0.f;
    }

    // A-frags: this wave's 16 rows x full K. m=l15, k=quad*8+j (16x16x32).
    const unsigned short* pa = Pn + (size_t)(rb + wave * 16 + l15) * NF + quad * 8;
    short8 afr[8];
#pragma unroll
    for (int ks = 0; ks < 8; ++ks)
        afr[ks] = *(const short8*)(pa + ks * 32);

    // Row classes byte-packed (rows quad*4 + r); same int4 across l15 (bcast).
    unsigned yis;
    {
        int4 v = *(const int4*)(y + rb + wave * 16 + quad * 4);
        yis = (unsigned)(v.x & 255) | ((unsigned)(v.y & 255) << 8) |
              ((unsigned)(v.z & 255) << 16) | ((unsigned)(v.w & 255) << 24);
    }

    float rA[4], rB[4];
#pragma unroll
    for (int r = 0; r < 4; ++r) { rA[r] = 0.f; rB[r] = 0.f; }

    __syncthreads();   // own-vmcnt drained by each wave -> both chunks + yc ready

#pragma unroll 1
    for (int c = 0; c < 2; ++c) {
        float4v acc[4];
#pragma unroll
        for (int b = 0; b < 4; ++b) acc[b] = (float4v){0.f, 0.f, 0.f, 0.f};

#pragma unroll
        for (int ks = 0; ks < 8; ++ks) {
            short8 fb[4];
#pragma unroll
            for (int tc = 0; tc < 4; ++tc)
                fb[tc] = *(const short8*)&Bs[c][(ks * 4 + quad) * 512 + (tc * 16 + l15) * 8];
#pragma unroll
            for (int tc = 0; tc < 4; ++tc)
                acc[tc] = __builtin_amdgcn_mfma_f32_16x16x32_bf16(
                    afr[ks], fb[tc], acc[tc], 0, 0, 0);
        }

        if (offdiag) {
            // Fused row+col epilogue; row/col panels disjoint -> no diag check.
#pragma unroll
            for (int tc = 0; tc < 4; ++tc) {
                const int jl = c * 64 + tc * 16 + l15;
                const int yj = yc[jl];
                float ca = 0.f, cb = 0.f;
#pragma unroll
                for (int r = 0; r < 4; ++r) {
                    const float s = acc[tc][r];
                    const int cls = (yis >> (8 * r)) & 255;
                    const bool same = (cls == yj);
                    const float e = exp2f(s * (same ? -SC2 : SC2));
                    rA[r] += same ? 0.f : e;
                    rB[r] += same ? e : 0.f;
                    ca += same ? 0.f : e;
                    cb += same ? e : 0.f;
                }
                // Sum over this wave's 16 rows (across the 4 quads).
                ca += __shfl_xor(ca, 16, 64); ca += __shfl_xor(ca, 32, 64);
                cb += __shfl_xor(cb, 16, 64); cb += __shfl_xor(cb, 32, 64);
                if (quad == 0) {   // 16 lanes, distinct jl -> native ds_add_f32
                    atomicAdd(&colA[jl], ca);
                    atomicAdd(&colB[jl], cb);
                }
            }
        } else {
            // Diagonal block: row-only (covers both orders in-panel), self-excl.
#pragma unroll
            for (int tc = 0; tc < 4; ++tc) {
                const int jl = c * 64 + tc * 16 + l15;
                const int yj = yc[jl];
                const int gj = cb0 + jl;
                const int gi0 = rb + wave * 16 + quad * 4;
#pragma unroll
                for (int r = 0; r < 4; ++r) {
                    const float s = acc[tc][r];
                    const int cls = (yis >> (8 * r)) & 255;
                    const bool same = (cls == yj);
                    const float e = exp2f(s * (same ? -SC2 : SC2));
                    rA[r] += same ? 0.f : e;
                    rB[r] += (same && (gi0 + r != gj)) ? e : 0.f;
                }
            }
        }
    }

    // Row side: butterfly over 16 col-lanes; quad leaders issue atomics.
#pragma unroll
    for (int r = 0; r < 4; ++r) {
#pragma unroll
        for (int off = 1; off < 16; off <<= 1) {
            rA[r] += __shfl_xor(rA[r], off, 64);
            rB[r] += __shfl_xor(rB[r], off, 64);
        }
    }
    if (l15 == 0) {
#pragma unroll
        for (int r = 0; r < 4; ++r) {
            const int gi = rb + wave * 16 + quad * 4 + r;
            atomicAdd(&Aacc[gi], rA[r]);
            atomicAdd(&Bacc[gi], rB[r]);
        }
    }

    // Column side: dump 128 A + 128 B partials to private slot (coalesced).
    if (offdiag) {
        __syncthreads();
        if (tid < 256) {
            float* cp = colPart + (size_t)bid * 256;
            cp[tid] = (tid < 128) ? colA[tid] : colB[tid - 128];
        }
    }
}

// Fused reduce+final: per-block ballot hist, column-partial reduce
// (2 threads/col), per-row loss, one atomicAdd into out per block.
// Group C2's col partials live at bid = C2*(C2+1)/2 + I for I in [0, C2).
__global__ __launch_bounds__(256)
void k_tail(const float* __restrict__ colPart, const float* __restrict__ Aacc,
            const float* __restrict__ Bacc, const int* __restrict__ y,
            float* __restrict__ out, int n) {
    __shared__ int hist[16];
    __shared__ float red[4];
    const int tid = threadIdx.x;
    if (tid < 16) hist[tid] = 0;
    __syncthreads();
    int loc[10];
#pragma unroll
    for (int cc = 0; cc < 10; ++cc) loc[cc] = 0;
    for (int i = tid; i < n; i += 256) {
        const int yv = y[i];
#pragma unroll
        for (int cc = 0; cc < 10; ++cc) {
            unsigned long long m = __ballot(yv == cc);
            if ((tid & 63) == 0) loc[cc] += __popcll(m);
        }
    }
    if ((tid & 63) == 0)
#pragma unroll
        for (int cc = 0; cc < 10; ++cc) atomicAdd(&hist[cc], loc[cc]);
    __syncthreads();

    const int jloc = tid >> 1, half = tid & 1;
    const int j = blockIdx.x * 128 + jloc;   // column/row 0..8191
    const int C2 = j >> 7, o = j & 127;
    const float* p = colPart + ((size_t)(C2 * (C2 + 1)) / 2 + half) * 256 + o;
    float sA = 0.f, sB = 0.f;
    for (int I = half; I < C2; I += 2) {
        sA += p[0];
        sB += p[128];
        p += 512;
    }
    sA += __shfl_xor(sA, 1, 64);
    sB += __shfl_xor(sB, 1, 64);

    float term = 0.f;
    if (half == 0) {
        const float M = __expf(0.5f * TINV);
        const int cc = hist[y[j] & 15];
        float a = Aacc[j] + sA;
        float b = Bacc[j] + sB;
        a = (n - cc) > 0 ? a : 1.0f;
        b = (cc - 1) > 0 ? b : 1.0f;
        term = log1pf(M * a * b);
    }
#pragma unroll
    for (int off = 32; off; off >>= 1) term += __shfl_xor(term, off, 64);
    if ((tid & 63) == 0) red[tid >> 6] = term;
    __syncthreads();
    if (tid == 0)
        atomicAdd(out, (red[0] + red[1] + red[2] + red[3]) / (float)n);
}

extern "C" void kernel_launch(void* const* d_in, const int* in_sizes, int n_in,
                              void* d_out, int out_size, void* d_ws, size_t ws_size,
                              hipStream_t stream) {
    const float* P = (const float*)d_in[0];
    const int* y   = (const int*)d_in[1];
    float* out     = (float*)d_out;
    const int n = in_sizes[1];  // 8192

    // ws: Pn bf16 [n*256] | Aacc f32 [n] | Bacc f32 [n] | colPart f32 [2080*256]
    unsigned short* Pn = (unsigned short*)d_ws;
    float* Aacc = (float*)((char*)d_ws + (size_t)n * NF * 2);
    float* Bacc = Aacc + n;
    float* colPart = Bacc + n;

    const int np = n / 128;                 // 64 panels of 128
    const int nblk = np * (np + 1) / 2;     // 2080 triangle blocks
    k_prep<<<n / 4, 256, 0, stream>>>(P, Pn, Aacc, out);
    k_main<<<nblk, 512, 0, stream>>>(Pn, y, Aacc, Bacc, colPart);
    k_tail<<<n / 128, 256, 0, stream>>>(colPart, Aacc, Bacc, y, out, n);
}

// Round 7
// 136.300 us; speedup vs baseline: 1.1760x; 1.0198x over previous
//
#include <hip/hip_runtime.h>
#include <hip/hip_bf16.h>

// n=8192 rows, d=256 feat, 10 classes.
// loss = mean_i log1p(exp(0.5/0.7) * A_i * B_i)
//   A_i = sum_{j: y_j!=y_i} exp(sim_ij/0.7), B_i = sum_{j!=i: y_j==y_i} exp(-sim_ij/0.7)
//   sim = rownorm(P) @ rownorm(P)^T
//
// R14: the ~65-70us floor was INVARIANT across R7->R13 because total LDS reads
// were invariant: reads/MFMA = 1/tr (row-tiles per wave); R13 halved MFMAs but
// also halved tr -> same 1.07 GB of ds_read_b128 (~21us of LDS pipe) + ~1M
// ds_bpermute (~7us) every round. Fix: wave tile 32x128 (tr=2, tc=8), 4 waves
// per 256-thr block, same 128x128 triangle grid (2080 blocks, I<=C2), same
// kc-major single-DMA-fill + one-barrier free-run structure as R13. Halves
// LDS reads (0.53 GB) AND wave count (8320) -> bpermute+issue halve too.
// Regs: afr 64 + acc 64 + fb 32 + rA/rB 16 + misc ~200 < 256 cap at (256,2).
// Spill tripwire: WRITE_SIZE must stay ~10 MB.

#define NF 256
#define TINV (1.0f / 0.7f)
#define SC2 2.0609929398439434f  // (1/0.7)*log2(e)

typedef __attribute__((ext_vector_type(8))) short short8;
typedef __attribute__((ext_vector_type(4))) float float4v;

typedef const __attribute__((address_space(1))) unsigned int glb_u32;
typedef __attribute__((address_space(3))) unsigned int lds_u32;

// One wave per row: normalize to bf16. Also zeroes accumulators and out.
__global__ __launch_bounds__(256)
void k_prep(const float* __restrict__ P, unsigned short* __restrict__ Pn,
            float* __restrict__ AB, float* __restrict__ out) {
    int wave = threadIdx.x >> 6, lane = threadIdx.x & 63;
    int row = blockIdx.x * 4 + wave;
    if (threadIdx.x < 8) AB[blockIdx.x * 8 + threadIdx.x] = 0.f;
    if (blockIdx.x == 0 && threadIdx.x == 0) out[0] = 0.f;
    float4 v = *(const float4*)(P + (size_t)row * NF + lane * 4);
    float sq = v.x * v.x + v.y * v.y + v.z * v.z + v.w * v.w;
#pragma unroll
    for (int off = 32; off; off >>= 1) sq += __shfl_xor(sq, off, 64);
    float r = rsqrtf(sq);
    __hip_bfloat16 h0 = __float2bfloat16(v.x * r), h1 = __float2bfloat16(v.y * r),
                   h2 = __float2bfloat16(v.z * r), h3 = __float2bfloat16(v.w * r);
    ushort4 o = { *(unsigned short*)&h0, *(unsigned short*)&h1,
                  *(unsigned short*)&h2, *(unsigned short*)&h3 };
    *(ushort4*)(Pn + (size_t)row * NF + lane * 4) = o;
}

__global__ __launch_bounds__(256, 2)
void k_main(const unsigned short* __restrict__ Pn, const int* __restrict__ y,
            float* __restrict__ Aacc, float* __restrict__ Bacc,
            float* __restrict__ colPart) {
    // Full B panel resident: 128 cols x K=256, kc-major:
    // ushort addr = (kc*128 + col)*8, kc in [0,32) (8 k's each). 64 KB.
    __shared__ __align__(16) unsigned short Bs[32 * 128 * 8];
    __shared__ int yc[128];
    __shared__ float colA[128], colB[128];

    const int tid = threadIdx.x;
    // Decode (I, C2): bid = C2*(C2+1)/2 + I, I in [0, C2].
    int bid = blockIdx.x;
    int C2 = (int)((sqrtf(8.0f * (float)bid + 1.0f) - 1.0f) * 0.5f);
    while ((C2 * (C2 + 1)) / 2 > bid) --C2;
    while (((C2 + 1) * (C2 + 2)) / 2 <= bid) ++C2;
    const int I = bid - (C2 * (C2 + 1)) / 2;
    const int rb = I * 128, cb0 = C2 * 128;
    const bool offdiag = (I < C2);   // uniform

    const int lane = tid & 63, wave = tid >> 6;   // 4 waves
    const int quad = lane >> 4, l15 = lane & 15;

    // DMA one 64-col half: 32 instrs (8 per wave), lane L -> col c*64+L.
    // Instr writes base + lane*16B; dst base = (kc*128 + c*64)*8 ushorts.
#define DMA_CHUNK(c)                                                         \
    {                                                                        \
        _Pragma("unroll")                                                    \
        for (int i = 0; i < 8; ++i) {                                        \
            const int kc = wave * 8 + i;                                     \
            const unsigned short* src =                                      \
                Pn + (size_t)(cb0 + (c) * 64 + lane) * NF + kc * 8;          \
            __builtin_amdgcn_global_load_lds((glb_u32*)src,                  \
                (lds_u32*)&Bs[(kc * 128 + (c) * 64) * 8], 16, 0, 0);         \
        }                                                                    \
    }

    DMA_CHUNK(0)
    DMA_CHUNK(1)

    if (tid < 128) {
        yc[tid] = y[cb0 + tid];
        colA[tid] = 0.f;
        colB[tid] = 0.f;
    }

    // A-frags: this wave's 32 rows x full K. m=l15, k=quad*8+j (16x16x32).
    const unsigned short* pa = Pn + (size_t)(rb + wave * 32 + l15) * NF + quad * 8;
    short8 afr[2][8];
#pragma unroll
    for (int tr = 0; tr < 2; ++tr)
#pragma unroll
        for (int ks = 0; ks < 8; ++ks)
            afr[tr][ks] = *(const short8*)(pa + (size_t)tr * 16 * NF + ks * 32);

    // Row classes byte-packed (rows tr*16 + quad*4 + r).
    unsigned yis[2];
#pragma unroll
    for (int tr = 0; tr < 2; ++tr) {
        int4 v = *(const int4*)(y + rb + wave * 32 + tr * 16 + quad * 4);
        yis[tr] = (unsigned)(v.x & 255) | ((unsigned)(v.y & 255) << 8) |
                  ((unsigned)(v.z & 255) << 16) | ((unsigned)(v.w & 255) << 24);
    }

    float rA[2][4], rB[2][4];
#pragma unroll
    for (int tr = 0; tr < 2; ++tr)
#pragma unroll
        for (int r = 0; r < 4; ++r) { rA[tr][r] = 0.f; rB[tr][r] = 0.f; }

    __syncthreads();   // each wave's own vmcnt drained before barrier -> Bs + yc ready

    // K-loop over full 128-col panel: each fb read feeds 2 MFMAs (tr=2).
    float4v acc[2][8];
#pragma unroll
    for (int a = 0; a < 2; ++a)
#pragma unroll
        for (int b = 0; b < 8; ++b) acc[a][b] = (float4v){0.f, 0.f, 0.f, 0.f};

#pragma unroll
    for (int ks = 0; ks < 8; ++ks) {
        short8 fb[8];
#pragma unroll
        for (int tc = 0; tc < 8; ++tc)
            fb[tc] = *(const short8*)&Bs[((ks * 4 + quad) * 128 + tc * 16 + l15) * 8];
#pragma unroll
        for (int tr = 0; tr < 2; ++tr)
#pragma unroll
            for (int tc = 0; tc < 8; ++tc)
                acc[tr][tc] = __builtin_amdgcn_mfma_f32_16x16x32_bf16(
                    afr[tr][ks], fb[tc], acc[tr][tc], 0, 0, 0);
    }

    if (offdiag) {
        // Fused row+col epilogue; row/col panels disjoint -> no diag check.
#pragma unroll
        for (int tc = 0; tc < 8; ++tc) {
            const int jl = tc * 16 + l15;
            const int yj = yc[jl];
            float ca = 0.f, cb = 0.f;
#pragma unroll
            for (int tr = 0; tr < 2; ++tr)
#pragma unroll
                for (int r = 0; r < 4; ++r) {
                    const float s = acc[tr][tc][r];
                    const int cls = (yis[tr] >> (8 * r)) & 255;
                    const bool same = (cls == yj);
                    const float e = exp2f(s * (same ? -SC2 : SC2));
                    rA[tr][r] += same ? 0.f : e;
                    rB[tr][r] += same ? e : 0.f;
                    ca += same ? 0.f : e;
                    cb += same ? e : 0.f;
                }
            // Sum over this wave's 32 rows (across the 4 quads).
            ca += __shfl_xor(ca, 16, 64); ca += __shfl_xor(ca, 32, 64);
            cb += __shfl_xor(cb, 16, 64); cb += __shfl_xor(cb, 32, 64);
            if (quad == 0) {   // 16 lanes, distinct jl -> native ds_add_f32
                atomicAdd(&colA[jl], ca);
                atomicAdd(&colB[jl], cb);
            }
        }
    } else {
        // Diagonal block: row-only (covers both orders in-panel), self-excl.
#pragma unroll
        for (int tc = 0; tc < 8; ++tc) {
            const int jl = tc * 16 + l15;
            const int yj = yc[jl];
            const int gj = cb0 + jl;
#pragma unroll
            for (int tr = 0; tr < 2; ++tr) {
                const int gi0 = rb + wave * 32 + tr * 16 + quad * 4;
#pragma unroll
                for (int r = 0; r < 4; ++r) {
                    const float s = acc[tr][tc][r];
                    const int cls = (yis[tr] >> (8 * r)) & 255;
                    const bool same = (cls == yj);
                    const float e = exp2f(s * (same ? -SC2 : SC2));
                    rA[tr][r] += same ? 0.f : e;
                    rB[tr][r] += (same && (gi0 + r != gj)) ? e : 0.f;
                }
            }
        }
    }

    // Row side: butterfly over 16 col-lanes; quad leaders issue atomics.
#pragma unroll
    for (int tr = 0; tr < 2; ++tr)
#pragma unroll
        for (int r = 0; r < 4; ++r) {
#pragma unroll
            for (int off = 1; off < 16; off <<= 1) {
                rA[tr][r] += __shfl_xor(rA[tr][r], off, 64);
                rB[tr][r] += __shfl_xor(rB[tr][r], off, 64);
            }
        }
    if (l15 == 0) {
#pragma unroll
        for (int tr = 0; tr < 2; ++tr)
#pragma unroll
            for (int r = 0; r < 4; ++r) {
                const int gi = rb + wave * 32 + tr * 16 + quad * 4 + r;
                atomicAdd(&Aacc[gi], rA[tr][r]);
                atomicAdd(&Bacc[gi], rB[tr][r]);
            }
    }

    // Column side: dump 128 A + 128 B partials to private slot (coalesced).
    if (offdiag) {
        __syncthreads();
        float* cp = colPart + (size_t)bid * 256;
        cp[tid] = (tid < 128) ? colA[tid] : colB[tid - 128];
    }
}

// Fused reduce+final: per-block ballot hist, column-partial reduce
// (2 threads/col), per-row loss, one atomicAdd into out per block.
// Group C2's col partials live at bid = C2*(C2+1)/2 + I for I in [0, C2).
__global__ __launch_bounds__(256)
void k_tail(const float* __restrict__ colPart, const float* __restrict__ Aacc,
            const float* __restrict__ Bacc, const int* __restrict__ y,
            float* __restrict__ out, int n) {
    __shared__ int hist[16];
    __shared__ float red[4];
    const int tid = threadIdx.x;
    if (tid < 16) hist[tid] = 0;
    __syncthreads();
    int loc[10];
#pragma unroll
    for (int cc = 0; cc < 10; ++cc) loc[cc] = 0;
    for (int i = tid; i < n; i += 256) {
        const int yv = y[i];
#pragma unroll
        for (int cc = 0; cc < 10; ++cc) {
            unsigned long long m = __ballot(yv == cc);
            if ((tid & 63) == 0) loc[cc] += __popcll(m);
        }
    }
    if ((tid & 63) == 0)
#pragma unroll
        for (int cc = 0; cc < 10; ++cc) atomicAdd(&hist[cc], loc[cc]);
    __syncthreads();

    const int jloc = tid >> 1, half = tid & 1;
    const int j = blockIdx.x * 128 + jloc;   // column/row 0..8191
    const int C2 = j >> 7, o = j & 127;
    const float* p = colPart + ((size_t)(C2 * (C2 + 1)) / 2 + half) * 256 + o;
    float sA = 0.f, sB = 0.f;
    for (int I = half; I < C2; I += 2) {
        sA += p[0];
        sB += p[128];
        p += 512;
    }
    sA += __shfl_xor(sA, 1, 64);
    sB += __shfl_xor(sB, 1, 64);

    float term = 0.f;
    if (half == 0) {
        const float M = __expf(0.5f * TINV);
        const int cc = hist[y[j] & 15];
        float a = Aacc[j] + sA;
        float b = Bacc[j] + sB;
        a = (n - cc) > 0 ? a : 1.0f;
        b = (cc - 1) > 0 ? b : 1.0f;
        term = log1pf(M * a * b);
    }
#pragma unroll
    for (int off = 32; off; off >>= 1) term += __shfl_xor(term, off, 64);
    if ((tid & 63) == 0) red[tid >> 6] = term;
    __syncthreads();
    if (tid == 0)
        atomicAdd(out, (red[0] + red[1] + red[2] + red[3]) / (float)n);
}

extern "C" void kernel_launch(void* const* d_in, const int* in_sizes, int n_in,
                              void* d_out, int out_size, void* d_ws, size_t ws_size,
                              hipStream_t stream) {
    const float* P = (const float*)d_in[0];
    const int* y   = (const int*)d_in[1];
    float* out     = (float*)d_out;
    const int n = in_sizes[1];  // 8192

    // ws: Pn bf16 [n*256] | Aacc f32 [n] | Bacc f32 [n] | colPart f32 [2080*256]
    unsigned short* Pn = (unsigned short*)d_ws;
    float* Aacc = (float*)((char*)d_ws + (size_t)n * NF * 2);
    float* Bacc = Aacc + n;
    float* colPart = Bacc + n;

    const int np = n / 128;                 // 64 panels of 128
    const int nblk = np * (np + 1) / 2;     // 2080 triangle blocks
    k_prep<<<n / 4, 256, 0, stream>>>(P, Pn, Aacc, out);
    k_main<<<nblk, 256, 0, stream>>>(Pn, y, Aacc, Bacc, colPart);
    k_tail<<<n / 128, 256, 0, stream>>>(colPart, Aacc, Bacc, y, out, n);
}